// Round 4
// baseline (510.599 us; speedup 1.0000x reference)
//
#include <hip/hip_runtime.h>
#include <math.h>

// CTreeC loss: DEPTH=7, V=255 states, B=64, T=50, vocab=5000.
// R4: single-launch producer/consumer. 64 scan blocks (blockIdx 0..63,
// dispatched first) + 3200 producer blocks, all 64-thread / 1-wave.
// Producers gather+exp one (b,t) row of extracted into ws and signal
// flags[b] with an agent-scope release; scan block b spins (agent-scope
// acquire) until flags[b]==len[b], then runs the linear-domain scan
// (R3 math, absmax 0.0): the per-step logC normalization telescopes, so
// dividing by S=sum_OUT(curr) in linear space and accumulating log(S)
// reproduces the reference exactly.
//
// Deadlock-safety: 64 spinning 1-wave blocks << 256 CU x 32 wave capacity;
// producer blocks always have slots, run to completion, and retire.
//
// Tree structure (in-order numbering), p = v+1:
//   START <=> p power of 2; END <=> p + (p&-p) == 256; OUT = non-END (247).
//   non-START x: s=ctz(p), j=x-2^s, k=ctz(p&(p-1)); sources {j-2^a: a<k}.

#define TT 50
#define BB 64
#define VOCAB 5000
#define NS 255
#define NSP 256

// ws layout: [0,1024) flags (uint per batch, padded), [1024, ...) ews
#define EWS_OFF_BYTES 1024
#define WS_NEEDED (EWS_OFF_BYTES + (size_t)BB * TT * NSP * 4)

__device__ __forceinline__ float wred_sum(float x) {
#pragma unroll
    for (int m = 32; m >= 1; m >>= 1) x += __shfl_xor(x, m);
    return x;
}

__global__ __launch_bounds__(64) void ctreec_fused_pc(
    const float* __restrict__ log_probs,
    const int* __restrict__ targets,
    const int* __restrict__ target_lengths,
    float* __restrict__ out,
    unsigned* __restrict__ flags,     // ws[0..63], pre-zeroed
    float* __restrict__ ews)          // ws + 1024
{
    const int bid = blockIdx.x;
    const int lane = threadIdx.x;

    if (bid >= BB) {
        // ---- producer: one (b,t) row ----
        const int bt = bid - BB;
        const int b = bt / TT;
        const int t = bt % TT;
        if (t >= target_lengths[b]) return;   // uniform; no signal needed
        const int tgt = targets[t * BB + b];
        const float* base = log_probs + (size_t)b * VOCAB + tgt;
        float* row = ews + (size_t)bt * NSP;
#pragma unroll
        for (int i = 0; i < 4; ++i) {
            const int v = lane + i * 64;
            float val = 0.0f;                 // pad slot v=255 contributes 0
            if (v < NS) val = __expf(base[(size_t)v * (BB * VOCAB)]);
            row[v] = val;                     // coalesced 256B/instr
        }
        __threadfence();                      // agent-scope release of row
        if (lane == 0)
            __hip_atomic_fetch_add(&flags[b], 1u, __ATOMIC_RELAXED,
                                   __HIP_MEMORY_SCOPE_AGENT);
        return;
    }

    // ---- consumer: scan for batch b ----
    const int b = bid;
    const int vbase = lane * 4;
    __shared__ float outv[NSP];

    const int len = target_lengths[b];

    // static tree structure for this lane's 4 nodes
    bool isend[4], isout[4];
    int kk[4], jj[4];
    float prev[4];
#pragma unroll
    for (int i = 0; i < 4; ++i) {
        int v = vbase + i;
        int p = v + 1;
        bool valid = (v < NS);
        bool pw2 = (p & (p - 1)) == 0;
        bool e_ = valid && ((p + (p & (-p))) == 256);
        isend[i] = e_;
        isout[i] = valid && !e_;
        prev[i] = (valid && pw2) ? 1.0f : 0.0f;
        if (valid && !pw2) {
            int s = __ffs(p) - 1;
            int q = p & (p - 1);
            kk[i] = __ffs(q) - 1;
            jj[i] = v - (1 << s);
        } else { kk[i] = 0; jj[i] = 0; }
    }

    // wait until all len rows of this batch are published
    while (__hip_atomic_load(&flags[b], __ATOMIC_RELAXED,
                             __HIP_MEMORY_SCOPE_AGENT) < (unsigned)len)
        __builtin_amdgcn_s_sleep(8);
    __threadfence();                          // acquire side

    const float4* ew = (const float4*)(ews + (size_t)b * TT * NSP);

    float acc = 0.0f;
    float4 eA = ew[lane];                               // prefetch t, t+1
    float4 eB = (len > 1) ? ew[64 + lane] : eA;
    for (int t = 0; t < len; ++t) {
        float4 cur = eA;
        eA = eB;
        if (t + 2 < len) eB = ew[(t + 2) * 64 + lane];  // prefetch depth 2

        float c[4];
        c[0] = prev[0] * cur.x;
        c[1] = prev[1] * cur.y;
        c[2] = prev[2] * cur.z;
        c[3] = prev[3] * cur.w;

        if (t == len - 1) {
            float s = 0.0f;
#pragma unroll
            for (int i = 0; i < 4; ++i)
                if (isend[i]) s += c[i];
            s = wred_sum(s);
            acc += __logf(s);
        } else {
            // stage unnormalized curr in LDS; overlaps with the reduction
            *(float4*)&outv[vbase] = make_float4(c[0], c[1], c[2], c[3]);
            float s = 0.0f;
#pragma unroll
            for (int i = 0; i < 4; ++i)
                if (isout[i]) s += c[i];
            s = wred_sum(s);
            acc += __logf(s);
            float rinv = 1.0f / s;   // scaling error telescopes out
            __syncthreads();         // 1-wave block: cheap
#pragma unroll
            for (int i = 0; i < 4; ++i) {
                float np_ = 0.0f;
                int bj = jj[i];
                int n = kk[i];
                for (int a = 0; a < n; ++a) np_ += outv[bj - (1 << a)];
                prev[i] = np_ * rinv;
            }
            __syncthreads();
        }
    }
    if (lane == 0) out[b] = -acc;
}

// ---- Fallback: R3 two-kernel path (used only if ws too small) ----
__global__ __launch_bounds__(256) void gather_kernel(
    const float* __restrict__ log_probs,
    const int* __restrict__ targets,
    const int* __restrict__ target_lengths,
    float* __restrict__ ews)
{
    const int bt = blockIdx.x;
    const int b = bt / TT;
    const int t = bt % TT;
    if (t >= target_lengths[b]) return;
    const int v = threadIdx.x;
    const int tgt = targets[t * BB + b];
    float val = 0.0f;
    if (v < NS)
        val = __expf(log_probs[(size_t)v * (BB * VOCAB) + (size_t)b * VOCAB + tgt]);
    ews[(size_t)bt * NSP + v] = val;
}

__global__ __launch_bounds__(64) void scan_kernel(
    const float* __restrict__ ews,
    const int* __restrict__ target_lengths,
    float* __restrict__ out)
{
    const int b = blockIdx.x;
    const int lane = threadIdx.x;
    const int vbase = lane * 4;
    __shared__ float outv[NSP];
    const int len = target_lengths[b];
    const float4* ew = (const float4*)(ews + (size_t)b * TT * NSP);
    bool isend[4], isout[4];
    int kk[4], jj[4];
    float prev[4];
#pragma unroll
    for (int i = 0; i < 4; ++i) {
        int v = vbase + i;
        int p = v + 1;
        bool valid = (v < NS);
        bool pw2 = (p & (p - 1)) == 0;
        bool e_ = valid && ((p + (p & (-p))) == 256);
        isend[i] = e_;
        isout[i] = valid && !e_;
        prev[i] = (valid && pw2) ? 1.0f : 0.0f;
        if (valid && !pw2) {
            int s = __ffs(p) - 1;
            int q = p & (p - 1);
            kk[i] = __ffs(q) - 1;
            jj[i] = v - (1 << s);
        } else { kk[i] = 0; jj[i] = 0; }
    }
    float acc = 0.0f;
    float4 eA = ew[lane];
    float4 eB = (len > 1) ? ew[64 + lane] : eA;
    for (int t = 0; t < len; ++t) {
        float4 cur = eA;
        eA = eB;
        if (t + 2 < len) eB = ew[(t + 2) * 64 + lane];
        float c[4];
        c[0] = prev[0] * cur.x;
        c[1] = prev[1] * cur.y;
        c[2] = prev[2] * cur.z;
        c[3] = prev[3] * cur.w;
        if (t == len - 1) {
            float s = 0.0f;
#pragma unroll
            for (int i = 0; i < 4; ++i)
                if (isend[i]) s += c[i];
            s = wred_sum(s);
            acc += __logf(s);
        } else {
            *(float4*)&outv[vbase] = make_float4(c[0], c[1], c[2], c[3]);
            float s = 0.0f;
#pragma unroll
            for (int i = 0; i < 4; ++i)
                if (isout[i]) s += c[i];
            s = wred_sum(s);
            acc += __logf(s);
            float rinv = 1.0f / s;
            __syncthreads();
#pragma unroll
            for (int i = 0; i < 4; ++i) {
                float np_ = 0.0f;
                int bj = jj[i];
                int n = kk[i];
                for (int a = 0; a < n; ++a) np_ += outv[bj - (1 << a)];
                prev[i] = np_ * rinv;
            }
            __syncthreads();
        }
    }
    if (lane == 0) out[b] = -acc;
}

extern "C" void kernel_launch(void* const* d_in, const int* in_sizes, int n_in,
                              void* d_out, int out_size, void* d_ws, size_t ws_size,
                              hipStream_t stream) {
    const float* log_probs = (const float*)d_in[0];       // 255*64*5000
    const int* targets = (const int*)d_in[1];             // 50*64
    const int* target_lengths = (const int*)d_in[2];      // 64
    float* out = (float*)d_out;                           // 64

    if (ws_size >= WS_NEEDED) {
        unsigned* flags = (unsigned*)d_ws;
        float* ews = (float*)((char*)d_ws + EWS_OFF_BYTES);
        hipMemsetAsync(d_ws, 0, EWS_OFF_BYTES, stream);   // zero flags
        ctreec_fused_pc<<<dim3(BB + BB * TT), dim3(64), 0, stream>>>(
            log_probs, targets, target_lengths, out, flags, ews);
    } else {
        // minimal-ws fallback: two-kernel path needs only ews
        float* ews = (float*)d_ws;
        gather_kernel<<<dim3(BB * TT), dim3(256), 0, stream>>>(
            log_probs, targets, target_lengths, ews);
        scan_kernel<<<dim3(BB), dim3(64), 0, stream>>>(
            ews, target_lengths, out);
    }
}